// Round 8
// baseline (701.159 us; speedup 1.0000x reference)
//
#include <hip/hip_runtime.h>
#include <hip/hip_bf16.h>
#include <stdint.h>

#define IN_DIM  4096
#define OUT_DIM 4096
#define M_DIM   16384   // 8*2048
#define BK      64
#define NT      (IN_DIM / BK)   // 64

typedef float f32x4 __attribute__((ext_vector_type(4)));
typedef short bf16x8 __attribute__((ext_vector_type(8)));
typedef short bf16x4 __attribute__((ext_vector_type(4)));
typedef int   i32x4 __attribute__((ext_vector_type(4)));

__device__ __constant__ float NF4_CODE_D[16] = {
    -1.0f, -0.6961928009986877f, -0.5250730514526367f, -0.39491748809814453f,
    -0.28444138169288635f, -0.18477343022823334f, -0.09105003625154495f, 0.0f,
    0.07958029955625534f, 0.16093020141124725f, 0.24611230194568634f,
    0.33791524171829224f, 0.44070982933044434f, 0.5626170039176941f,
    0.7229568362236023f, 1.0f};

static __device__ __forceinline__ ushort f2bf(float f) {
  union { float f; uint32_t u; } v; v.f = f;
  uint32_t r = v.u + 0x7FFFu + ((v.u >> 16) & 1u);
  return (ushort)(r >> 16);
}

// ---------- merged prep: blocks [0,8192) dequant W; [8192,40960) cvt x ------
#define NB_W 8192
__global__ void prep(const float* __restrict__ x, const int* __restrict__ q,
                     const float* __restrict__ am, ushort* __restrict__ xb,
                     ushort* __restrict__ w) {
  if (blockIdx.x < NB_W) {
    __shared__ float code[16];
    if (threadIdx.x < 16) code[threadIdx.x] = NF4_CODE_D[threadIdx.x];
    __syncthreads();
    size_t t = (size_t)blockIdx.x * 256 + threadIdx.x;
    size_t base = t * 8;
    i32x4 qa = *(const i32x4*)(q + base);
    i32x4 qb = *(const i32x4*)(q + base + 4);
    float s = am[base >> 6];
    bf16x8 o;
    o[0] = (short)f2bf(code[qa[0] & 15] * s);
    o[1] = (short)f2bf(code[qa[1] & 15] * s);
    o[2] = (short)f2bf(code[qa[2] & 15] * s);
    o[3] = (short)f2bf(code[qa[3] & 15] * s);
    o[4] = (short)f2bf(code[qb[0] & 15] * s);
    o[5] = (short)f2bf(code[qb[1] & 15] * s);
    o[6] = (short)f2bf(code[qb[2] & 15] * s);
    o[7] = (short)f2bf(code[qb[3] & 15] * s);
    *(bf16x8*)(w + base) = o;
  } else {
    size_t t = (size_t)(blockIdx.x - NB_W) * 256 + threadIdx.x;
    size_t base = t * 8;
    f32x4 a = *(const f32x4*)(x + base);
    f32x4 b = *(const f32x4*)(x + base + 4);
    bf16x8 o;
    o[0] = (short)f2bf(a[0]); o[1] = (short)f2bf(a[1]);
    o[2] = (short)f2bf(a[2]); o[3] = (short)f2bf(a[3]);
    o[4] = (short)f2bf(b[0]); o[5] = (short)f2bf(b[1]);
    o[6] = (short)f2bf(b[2]); o[7] = (short)f2bf(b[3]);
    *(bf16x8*)(xb + base) = o;
  }
}

// ---------------- global_load_lds helper (16B direct-to-LDS) ---------------
static __device__ __forceinline__ void llds16(const ushort* g, ushort* l) {
  __builtin_amdgcn_global_load_lds(
      (const __attribute__((address_space(1))) void*)g,
      (__attribute__((address_space(3))) void*)l, 16, 0, 0);
}

// ===========================================================================
// 256x256 GEMM, minimal-sync double-buffered schedule.
// y[M][N] = Xb[M][K] * W[N][K]^T, bf16 MFMA 16x16x32, 8 waves (2Mx4N).
// Per K-tile t (cur = t&1):
//   [stage ALL of tile t+1 -> nxt : 8 global_load_lds]
//   vmcnt(8)   // drains tile t's 8 loads (staged last iter); keeps t+1's 8
//   s_barrier  // tile t LDS visible to all waves; also publishes that nxt's
//              //   previous readers (tile t-1, before last end-barrier) done
//   [24 ds_read_b128 + 64 MFMA, UNFENCED: compiler emits fine lgkmcnt;
//    waves drift within the region so reads overlap other waves' MFMAs]
//   s_barrier  // protects cur from iter t+1's staging (WAR). Reads are all
//              //   register-consumed by MFMAs before this point.
// 2 barriers + 1 counted vmcnt per tile; never vmcnt(0) in the loop.
// Flight per staged tile: one full tile body (~2500 cy) >> HBM latency.
// Swizzle (T2): LDS slot s of row r holds global slot s^(r&7); applied on
// the global source col at staging and on the ds_read address (rule #21).
// ===========================================================================
__global__ __launch_bounds__(512, 2) void gemm256(const ushort* __restrict__ Xb,
                                                  const ushort* __restrict__ W,
                                                  float* __restrict__ Y) {
  __shared__ ushort As[2][256 * BK];   // 2 x 32 KB
  __shared__ ushort Bs[2][256 * BK];   // 2 x 32 KB

  const int tid  = threadIdx.x;
  const int lane = tid & 63;
  const int wid  = tid >> 6;        // 0..7
  const int wr   = wid >> 2;        // 0..1
  const int wc   = wid & 3;         // 0..3
  const int l15  = lane & 15;
  const int kg   = lane >> 4;       // 0..3
  const int l7   = lane & 7;

  // bijective XCD swizzle (1024 wgs, 1024%8==0), tn-major within tm.
  const int bid = blockIdx.x;
  const int wg  = (bid & 7) * 128 + (bid >> 3);
  const int tm  = wg >> 4;          // 0..63
  const int tn  = wg & 15;          // 0..15
  const size_t row0 = (size_t)tm * 256;
  const size_t col0 = (size_t)tn * 256;

  const int srow  = tid >> 3;                       // 0..63
  const int scol8 = ((tid & 7) ^ (srow & 7)) * 8;   // pre-swizzled src col
  const int wbase = wid << 9;                       // wave LDS base (ushorts)

  f32x4  acc[8][4] = {};
  bf16x8 aA[4][2], aB[4][2], b0[2][2], b1[2][2];

#define BARX()  asm volatile("s_barrier" ::: "memory")
#define VMC(n)  asm volatile("s_waitcnt vmcnt(" #n ")" ::: "memory")

#define STAGE_A(kt, h, nb) do { \
    llds16(Xb + (row0 + (h)*128 +  0 + srow) * IN_DIM + (kt)*BK + scol8, \
           &As[nb][(h)*8192 +    0 + wbase]); \
    llds16(Xb + (row0 + (h)*128 + 64 + srow) * IN_DIM + (kt)*BK + scol8, \
           &As[nb][(h)*8192 + 4096 + wbase]); \
  } while (0)

#define STAGE_B(kt, h, nb) do { \
    llds16(W + (col0 + (h)*128 +  0 + srow) * IN_DIM + (kt)*BK + scol8, \
           &Bs[nb][(h)*8192 +    0 + wbase]); \
    llds16(W + (col0 + (h)*128 + 64 + srow) * IN_DIM + (kt)*BK + scol8, \
           &Bs[nb][(h)*8192 + 4096 + wbase]); \
  } while (0)

#define LDA_(dst, nb, mh) do { \
    _Pragma("unroll") for (int mi = 0; mi < 4; ++mi) \
    _Pragma("unroll") for (int ks = 0; ks < 2; ++ks) \
      dst[mi][ks] = *(const bf16x8*)&As[nb][((mh)*128 + wr*64 + mi*16 + l15) * BK \
                                            + (((ks*4 + kg) ^ l7) * 8)]; \
  } while (0)

#define LDB_(dst, nb, nh) do { \
    _Pragma("unroll") for (int ni = 0; ni < 2; ++ni) \
    _Pragma("unroll") for (int ks = 0; ks < 2; ++ks) \
      dst[ni][ks] = *(const bf16x8*)&Bs[nb][((nh)*128 + wc*32 + ni*16 + l15) * BK \
                                            + (((ks*4 + kg) ^ l7) * 8)]; \
  } while (0)

#define QUAD(mh, nh, aR, bR) do { \
    _Pragma("unroll") for (int mi = 0; mi < 4; ++mi) \
    _Pragma("unroll") for (int ni = 0; ni < 2; ++ni) \
    _Pragma("unroll") for (int ks = 0; ks < 2; ++ks) \
      acc[(mh)*4 + mi][(nh)*2 + ni] = __builtin_amdgcn_mfma_f32_16x16x32_bf16( \
          aR[mi][ks], bR[ni][ks], acc[(mh)*4 + mi][(nh)*2 + ni], 0, 0, 0); \
  } while (0)

  // ---- prologue: stage tile0 -> buf0 (8 loads) ----
  STAGE_A(0, 0, 0); STAGE_B(0, 0, 0); STAGE_A(0, 1, 0); STAGE_B(0, 1, 0);

  // ---- main loop: tiles 0..NT-2; iter t stages t+1 -> nxt ----
#pragma unroll 1
  for (int t = 0; t < NT - 1; ++t) {
    const int cur = t & 1, nxt = cur ^ 1;
    // stage next tile (8 loads)
    STAGE_A(t + 1, 0, nxt); STAGE_B(t + 1, 0, nxt);
    STAGE_A(t + 1, 1, nxt); STAGE_B(t + 1, 1, nxt);
    VMC(8);      // drain tile t (oldest 8); keep t+1's 8 in flight
    BARX();      // tile t visible to all waves
    // fused compute region: compiler schedules reads vs MFMAs freely
    LDA_(aA, cur, 0); LDB_(b0, cur, 0);
    QUAD(0, 0, aA, b0);
    LDB_(b1, cur, 1);
    QUAD(0, 1, aA, b1);
    LDA_(aB, cur, 1);
    QUAD(1, 1, aB, b1);
    QUAD(1, 0, aB, b0);
    BARX();      // WAR fence: cur free for iter t+1's staging
  }

  // ---- peeled last tile (NT-1, buf = (NT-1)&1 = 1): drain and compute ----
  VMC(0);
  BARX();
  LDA_(aA, 1, 0); LDB_(b0, 1, 0);
  QUAD(0, 0, aA, b0);
  LDB_(b1, 1, 1);
  QUAD(0, 1, aA, b1);
  LDA_(aB, 1, 1);
  QUAD(1, 1, aB, b1);
  QUAD(1, 0, aB, b0);

#undef QUAD
#undef LDB_
#undef LDA_
#undef STAGE_B
#undef STAGE_A

  // ---- epilogue: row = mh*128 + wr*64 + mi*16 + kg*4 + v,
  //                col = nh*128 + wc*32 + ni*16 + l15
  float* yb = Y + (row0 + wr * 64 + kg * 4) * OUT_DIM + col0 + wc * 32 + l15;
#pragma unroll
  for (int mh = 0; mh < 2; ++mh)
#pragma unroll
    for (int mi = 0; mi < 4; ++mi)
#pragma unroll
      for (int nh = 0; nh < 2; ++nh)
#pragma unroll
        for (int ni = 0; ni < 2; ++ni)
#pragma unroll
          for (int v = 0; v < 4; ++v)
            yb[(size_t)(mh * 128 + mi * 16 + v) * OUT_DIM + nh * 128 + ni * 16] =
                acc[mh * 4 + mi][nh * 2 + ni][v];
}

// ---------------- fallback (ws too small): 128^2 fp32-A reg-staged ---------
__global__ void gemm_fb(const float* __restrict__ X, const ushort* __restrict__ W,
                        float* __restrict__ Y) {
  __shared__ ushort Af[128 * 64];
  __shared__ ushort Bf[128 * 64];
  const int tid  = threadIdx.x;
  const int lane = tid & 63;
  const int wid  = tid >> 6;
  const int wr   = wid >> 1, wc = wid & 1;
  const int bid  = blockIdx.x;
  const int tm   = bid / 32, tn = bid % 32;
  const size_t row0 = (size_t)tm * 128, col0 = (size_t)tn * 128;
  f32x4 acc[4][4] = {};
  const int arow = lane & 15, kgrp = lane >> 4;
  const int srow = lane >> 3, scol = (lane & 7) * 8;
  for (int k0 = 0; k0 < IN_DIM; k0 += 64) {
    f32x4 r[8];
#pragma unroll
    for (int i = 0; i < 8; ++i)
      r[i] = *(const f32x4*)(X + (row0 + i * 16 + (tid >> 4)) * IN_DIM + k0 + (tid & 15) * 4);
#pragma unroll
    for (int i = 0; i < 8; ++i) {
      bf16x4 o;
      o[0] = (short)f2bf(r[i][0]); o[1] = (short)f2bf(r[i][1]);
      o[2] = (short)f2bf(r[i][2]); o[3] = (short)f2bf(r[i][3]);
      *(bf16x4*)&Af[(i * 16 + (tid >> 4)) * 64 + (tid & 15) * 4] = o;
    }
#pragma unroll
    for (int i = 0; i < 4; ++i) {
      const int c = wid * 4 + i;
      llds16(W + (col0 + c * 8 + srow) * IN_DIM + k0 + scol, Bf + c * 512);
    }
    __syncthreads();
#pragma unroll
    for (int ks = 0; ks < 2; ++ks) {
      bf16x8 a[4], b[4];
#pragma unroll
      for (int m = 0; m < 4; ++m)
        a[m] = *(const bf16x8*)&Af[(wr * 64 + m * 16 + arow) * 64 + ks * 32 + kgrp * 8];
#pragma unroll
      for (int n = 0; n < 4; ++n)
        b[n] = *(const bf16x8*)&Bf[(wc * 64 + n * 16 + arow) * 64 + ks * 32 + kgrp * 8];
#pragma unroll
      for (int m = 0; m < 4; ++m)
#pragma unroll
        for (int n = 0; n < 4; ++n)
          acc[m][n] = __builtin_amdgcn_mfma_f32_16x16x32_bf16(a[m], b[n], acc[m][n], 0, 0, 0);
    }
    __syncthreads();
  }
  float* yb = Y + (row0 + wr * 64) * OUT_DIM + col0 + wc * 64;
  const int crow = (lane >> 4) * 4, ccol = lane & 15;
#pragma unroll
  for (int m = 0; m < 4; ++m)
#pragma unroll
    for (int n = 0; n < 4; ++n)
#pragma unroll
      for (int v = 0; v < 4; ++v)
        yb[(size_t)(m * 16 + crow + v) * OUT_DIM + n * 16 + ccol] = acc[m][n][v];
}

extern "C" void kernel_launch(void* const* d_in, const int* in_sizes, int n_in,
                              void* d_out, int out_size, void* d_ws, size_t ws_size,
                              hipStream_t stream) {
  const float* x  = (const float*)d_in[0];
  const int*   q  = (const int*)d_in[1];
  const float* am = (const float*)d_in[2];
  float* y = (float*)d_out;

  ushort* w = (ushort*)d_ws;
  const size_t WB = (size_t)OUT_DIM * IN_DIM * sizeof(ushort);   // 33.5 MB
  const size_t XB = (size_t)M_DIM * IN_DIM * sizeof(ushort);     // 134 MB

  if (ws_size >= WB + XB) {
    ushort* xb = (ushort*)((char*)d_ws + WB);
    const int nb = NB_W + (int)((size_t)M_DIM * IN_DIM / 8 / 256);  // 40960
    prep<<<nb, 256, 0, stream>>>(x, q, am, xb, w);
    gemm256<<<(M_DIM / 256) * (OUT_DIM / 256), 512, 0, stream>>>(xb, w, y);
  } else {
    prep<<<NB_W, 256, 0, stream>>>(x, q, am, nullptr, w);
    gemm_fb<<<(M_DIM / 128) * (OUT_DIM / 128), 256, 0, stream>>>(x, w, y);
  }
}

// Round 9
// 583.411 us; speedup vs baseline: 1.2018x; 1.2018x over previous
//
#include <hip/hip_runtime.h>
#include <hip/hip_bf16.h>
#include <stdint.h>

#define IN_DIM  4096
#define OUT_DIM 4096
#define M_DIM   16384   // 8*2048
#define BK      64
#define NT      (IN_DIM / BK)   // 64

typedef float f32x4 __attribute__((ext_vector_type(4)));
typedef short bf16x8 __attribute__((ext_vector_type(8)));
typedef short bf16x4 __attribute__((ext_vector_type(4)));
typedef int   i32x4 __attribute__((ext_vector_type(4)));

__device__ __constant__ float NF4_CODE_D[16] = {
    -1.0f, -0.6961928009986877f, -0.5250730514526367f, -0.39491748809814453f,
    -0.28444138169288635f, -0.18477343022823334f, -0.09105003625154495f, 0.0f,
    0.07958029955625534f, 0.16093020141124725f, 0.24611230194568634f,
    0.33791524171829224f, 0.44070982933044434f, 0.5626170039176941f,
    0.7229568362236023f, 1.0f};

static __device__ __forceinline__ ushort f2bf(float f) {
  union { float f; uint32_t u; } v; v.f = f;
  uint32_t r = v.u + 0x7FFFu + ((v.u >> 16) & 1u);
  return (ushort)(r >> 16);
}

// ---------- merged prep: blocks [0,8192) dequant W; [8192,40960) cvt x ------
#define NB_W 8192
__global__ void prep(const float* __restrict__ x, const int* __restrict__ q,
                     const float* __restrict__ am, ushort* __restrict__ xb,
                     ushort* __restrict__ w) {
  if (blockIdx.x < NB_W) {
    __shared__ float code[16];
    if (threadIdx.x < 16) code[threadIdx.x] = NF4_CODE_D[threadIdx.x];
    __syncthreads();
    size_t t = (size_t)blockIdx.x * 256 + threadIdx.x;
    size_t base = t * 8;
    i32x4 qa = *(const i32x4*)(q + base);
    i32x4 qb = *(const i32x4*)(q + base + 4);
    float s = am[base >> 6];
    bf16x8 o;
    o[0] = (short)f2bf(code[qa[0] & 15] * s);
    o[1] = (short)f2bf(code[qa[1] & 15] * s);
    o[2] = (short)f2bf(code[qa[2] & 15] * s);
    o[3] = (short)f2bf(code[qa[3] & 15] * s);
    o[4] = (short)f2bf(code[qb[0] & 15] * s);
    o[5] = (short)f2bf(code[qb[1] & 15] * s);
    o[6] = (short)f2bf(code[qb[2] & 15] * s);
    o[7] = (short)f2bf(code[qb[3] & 15] * s);
    *(bf16x8*)(w + base) = o;
  } else {
    size_t t = (size_t)(blockIdx.x - NB_W) * 256 + threadIdx.x;
    size_t base = t * 8;
    f32x4 a = *(const f32x4*)(x + base);
    f32x4 b = *(const f32x4*)(x + base + 4);
    bf16x8 o;
    o[0] = (short)f2bf(a[0]); o[1] = (short)f2bf(a[1]);
    o[2] = (short)f2bf(a[2]); o[3] = (short)f2bf(a[3]);
    o[4] = (short)f2bf(b[0]); o[5] = (short)f2bf(b[1]);
    o[6] = (short)f2bf(b[2]); o[7] = (short)f2bf(b[3]);
    *(bf16x8*)(xb + base) = o;
  }
}

// ---------------- global_load_lds helper (16B direct-to-LDS) ---------------
static __device__ __forceinline__ void llds16(const ushort* g, ushort* l) {
  __builtin_amdgcn_global_load_lds(
      (const __attribute__((address_space(1))) void*)g,
      (__attribute__((address_space(3))) void*)l, 16, 0, 0);
}

// ===========================================================================
// 256x256 GEMM, read-ahead pipelined 4-phase schedule (R3 — session best:
// 526 us, MfmaUtil 47.5%, 0 bank conflicts, ~1050 TF).
// y[M][N] = Xb[M][K] * W[N][K]^T, bf16 MFMA 16x16x32, 8 waves (2Mx4N).
// Per-wave output: rows {wr*64..+63} U {128+wr*64..+63},
//                  cols {wc*32..+31} U {128+wc*32..+31}
// so register buffer aA/aB/b0/b1 maps 1:1 to staged half-tile A0/A1/B0/B1.
// Per K-tile t (4 phases, ONE barrier each):
//  P1: ST A1(t+1)->nxt; vmcnt(4); bar; read b1,aB (for P2/P3); Q00(aA,b0)
//  P2: ST B0(t+1)->nxt; bar;                                   Q01(aA,b1)
//  P3: ST B1(t+1)->nxt; bar;                                   Q11(aB,b1)
//  P4: ST A0(t+2)->cur; vmcnt(4); bar; Q10(aB,b0); read aA,b0 (for t+1)
// Key property (vs R4/R5/R7/R8 which all regressed): fragment reads are
// issued right AFTER a barrier and BEFORE that phase's MFMA cluster — the
// barrier prevents hipcc from sinking the reads below the MFMAs, so one
// wave's LDS drain overlaps other waves' MFMA. vmcnt ledger: @P1 in-flight
// {B1(t),A0,A1(t+1)}=6 -> vmcnt(4) drains B1(t); @P4 in-flight 10 ->
// vmcnt(4) drains A0/A1/B0(t+1). Never vmcnt(0) in the loop.
// Swizzle (T2): LDS slot s of row r holds global slot s^(r&7); applied on
// the global source col at staging and on the ds_read address (rule #21).
// ===========================================================================
__global__ __launch_bounds__(512, 2) void gemm256(const ushort* __restrict__ Xb,
                                                  const ushort* __restrict__ W,
                                                  float* __restrict__ Y) {
  __shared__ ushort As[2][256 * BK];   // 2 x 32 KB
  __shared__ ushort Bs[2][256 * BK];   // 2 x 32 KB

  const int tid  = threadIdx.x;
  const int lane = tid & 63;
  const int wid  = tid >> 6;        // 0..7
  const int wr   = wid >> 2;        // 0..1
  const int wc   = wid & 3;         // 0..3
  const int l15  = lane & 15;
  const int kg   = lane >> 4;       // 0..3
  const int l7   = lane & 7;

  // bijective XCD swizzle (1024 wgs, 1024%8==0), tn-major within tm.
  const int bid = blockIdx.x;
  const int wg  = (bid & 7) * 128 + (bid >> 3);
  const int tm  = wg >> 4;          // 0..63
  const int tn  = wg & 15;          // 0..15
  const size_t row0 = (size_t)tm * 256;
  const size_t col0 = (size_t)tn * 256;

  const int srow  = tid >> 3;                       // 0..63
  const int scol8 = ((tid & 7) ^ (srow & 7)) * 8;   // pre-swizzled src col
  const int wbase = wid << 9;                       // wave LDS base (ushorts)

  f32x4  acc[8][4] = {};
  bf16x8 aA[4][2], aB[4][2], b0[2][2], b1[2][2];

#define BARX()  __builtin_amdgcn_s_barrier()
#define VMC(n)  asm volatile("s_waitcnt vmcnt(" #n ")" ::: "memory")
#define PRI1()  __builtin_amdgcn_s_setprio(1)
#define PRI0()  __builtin_amdgcn_s_setprio(0)

#define STAGE_A(kt, h, nb) do { \
    llds16(Xb + (row0 + (h)*128 +  0 + srow) * IN_DIM + (kt)*BK + scol8, \
           &As[nb][(h)*8192 +    0 + wbase]); \
    llds16(Xb + (row0 + (h)*128 + 64 + srow) * IN_DIM + (kt)*BK + scol8, \
           &As[nb][(h)*8192 + 4096 + wbase]); \
  } while (0)

#define STAGE_B(kt, h, nb) do { \
    llds16(W + (col0 + (h)*128 +  0 + srow) * IN_DIM + (kt)*BK + scol8, \
           &Bs[nb][(h)*8192 +    0 + wbase]); \
    llds16(W + (col0 + (h)*128 + 64 + srow) * IN_DIM + (kt)*BK + scol8, \
           &Bs[nb][(h)*8192 + 4096 + wbase]); \
  } while (0)

#define LDA_(dst, nb, mh) do { \
    _Pragma("unroll") for (int mi = 0; mi < 4; ++mi) \
    _Pragma("unroll") for (int ks = 0; ks < 2; ++ks) \
      dst[mi][ks] = *(const bf16x8*)&As[nb][((mh)*128 + wr*64 + mi*16 + l15) * BK \
                                            + (((ks*4 + kg) ^ l7) * 8)]; \
  } while (0)

#define LDB_(dst, nb, nh) do { \
    _Pragma("unroll") for (int ni = 0; ni < 2; ++ni) \
    _Pragma("unroll") for (int ks = 0; ks < 2; ++ks) \
      dst[ni][ks] = *(const bf16x8*)&Bs[nb][((nh)*128 + wc*32 + ni*16 + l15) * BK \
                                            + (((ks*4 + kg) ^ l7) * 8)]; \
  } while (0)

#define QUAD(mh, nh, aR, bR) do { PRI1(); \
    _Pragma("unroll") for (int mi = 0; mi < 4; ++mi) \
    _Pragma("unroll") for (int ni = 0; ni < 2; ++ni) \
    _Pragma("unroll") for (int ks = 0; ks < 2; ++ks) \
      acc[(mh)*4 + mi][(nh)*2 + ni] = __builtin_amdgcn_mfma_f32_16x16x32_bf16( \
          aR[mi][ks], bR[ni][ks], acc[(mh)*4 + mi][(nh)*2 + ni], 0, 0, 0); \
    PRI0(); } while (0)

  // ---- prologue: buf0 full + A0(1); leave A0(1) in flight ----
  STAGE_A(0, 0, 0); STAGE_A(0, 1, 0);
  STAGE_B(0, 0, 0); STAGE_B(0, 1, 0);
  STAGE_A(1, 0, 1);
  VMC(2); BARX();
  LDA_(aA, 0, 0); LDB_(b0, 0, 0);

  // ---- main loop: tiles 0..NT-2 ----
#pragma unroll 1
  for (int t = 0; t < NT - 1; ++t) {
    const int cur = t & 1, nxt = cur ^ 1;
    // P1
    STAGE_A(t + 1, 1, nxt);
    VMC(4); BARX();
    LDB_(b1, cur, 1); LDA_(aB, cur, 1);
    QUAD(0, 0, aA, b0);
    // P2
    STAGE_B(t + 1, 0, nxt);
    BARX();
    QUAD(0, 1, aA, b1);
    // P3
    STAGE_B(t + 1, 1, nxt);
    BARX();
    QUAD(1, 1, aB, b1);
    // P4
    if (t < NT - 2) {
      STAGE_A(t + 2, 0, cur);
      VMC(4);
    } else {
      VMC(2);
    }
    BARX();
    QUAD(1, 0, aB, b0);
    LDA_(aA, nxt, 0); LDB_(b0, nxt, 0);   // reads for tile t+1 (WAR renamed)
  }

  // ---- peeled tile NT-1 (buf1): no staging ----
  VMC(0); BARX();
  LDB_(b1, 1, 1); LDA_(aB, 1, 1);
  QUAD(0, 0, aA, b0);
  QUAD(0, 1, aA, b1);
  QUAD(1, 1, aB, b1);
  QUAD(1, 0, aB, b0);

#undef QUAD
#undef LDB_
#undef LDA_
#undef STAGE_B
#undef STAGE_A

  // ---- epilogue: row = mh*128 + wr*64 + mi*16 + kg*4 + v,
  //                col = nh*128 + wc*32 + ni*16 + l15
  float* yb = Y + (row0 + wr * 64 + kg * 4) * OUT_DIM + col0 + wc * 32 + l15;
#pragma unroll
  for (int mh = 0; mh < 2; ++mh)
#pragma unroll
    for (int mi = 0; mi < 4; ++mi)
#pragma unroll
      for (int nh = 0; nh < 2; ++nh)
#pragma unroll
        for (int ni = 0; ni < 2; ++ni)
#pragma unroll
          for (int v = 0; v < 4; ++v)
            yb[(size_t)(mh * 128 + mi * 16 + v) * OUT_DIM + nh * 128 + ni * 16] =
                acc[mh * 4 + mi][nh * 2 + ni][v];
}

// ---------------- fallback (ws too small): 128^2 fp32-A reg-staged ---------
__global__ void gemm_fb(const float* __restrict__ X, const ushort* __restrict__ W,
                        float* __restrict__ Y) {
  __shared__ ushort Af[128 * 64];
  __shared__ ushort Bf[128 * 64];
  const int tid  = threadIdx.x;
  const int lane = tid & 63;
  const int wid  = tid >> 6;
  const int wr   = wid >> 1, wc = wid & 1;
  const int bid  = blockIdx.x;
  const int tm   = bid / 32, tn = bid % 32;
  const size_t row0 = (size_t)tm * 128, col0 = (size_t)tn * 128;
  f32x4 acc[4][4] = {};
  const int arow = lane & 15, kgrp = lane >> 4;
  const int srow = lane >> 3, scol = (lane & 7) * 8;
  for (int k0 = 0; k0 < IN_DIM; k0 += 64) {
    f32x4 r[8];
#pragma unroll
    for (int i = 0; i < 8; ++i)
      r[i] = *(const f32x4*)(X + (row0 + i * 16 + (tid >> 4)) * IN_DIM + k0 + (tid & 15) * 4);
#pragma unroll
    for (int i = 0; i < 8; ++i) {
      bf16x4 o;
      o[0] = (short)f2bf(r[i][0]); o[1] = (short)f2bf(r[i][1]);
      o[2] = (short)f2bf(r[i][2]); o[3] = (short)f2bf(r[i][3]);
      *(bf16x4*)&Af[(i * 16 + (tid >> 4)) * 64 + (tid & 15) * 4] = o;
    }
#pragma unroll
    for (int i = 0; i < 4; ++i) {
      const int c = wid * 4 + i;
      llds16(W + (col0 + c * 8 + srow) * IN_DIM + k0 + scol, Bf + c * 512);
    }
    __syncthreads();
#pragma unroll
    for (int ks = 0; ks < 2; ++ks) {
      bf16x8 a[4], b[4];
#pragma unroll
      for (int m = 0; m < 4; ++m)
        a[m] = *(const bf16x8*)&Af[(wr * 64 + m * 16 + arow) * 64 + ks * 32 + kgrp * 8];
#pragma unroll
      for (int n = 0; n < 4; ++n)
        b[n] = *(const bf16x8*)&Bf[(wc * 64 + n * 16 + arow) * 64 + ks * 32 + kgrp * 8];
#pragma unroll
      for (int m = 0; m < 4; ++m)
#pragma unroll
        for (int n = 0; n < 4; ++n)
          acc[m][n] = __builtin_amdgcn_mfma_f32_16x16x32_bf16(a[m], b[n], acc[m][n], 0, 0, 0);
    }
    __syncthreads();
  }
  float* yb = Y + (row0 + wr * 64) * OUT_DIM + col0 + wc * 64;
  const int crow = (lane >> 4) * 4, ccol = lane & 15;
#pragma unroll
  for (int m = 0; m < 4; ++m)
#pragma unroll
    for (int n = 0; n < 4; ++n)
#pragma unroll
      for (int v = 0; v < 4; ++v)
        yb[(size_t)(m * 16 + crow + v) * OUT_DIM + n * 16 + ccol] = acc[m][n][v];
}

extern "C" void kernel_launch(void* const* d_in, const int* in_sizes, int n_in,
                              void* d_out, int out_size, void* d_ws, size_t ws_size,
                              hipStream_t stream) {
  const float* x  = (const float*)d_in[0];
  const int*   q  = (const int*)d_in[1];
  const float* am = (const float*)d_in[2];
  float* y = (float*)d_out;

  ushort* w = (ushort*)d_ws;
  const size_t WB = (size_t)OUT_DIM * IN_DIM * sizeof(ushort);   // 33.5 MB
  const size_t XB = (size_t)M_DIM * IN_DIM * sizeof(ushort);     // 134 MB

  if (ws_size >= WB + XB) {
    ushort* xb = (ushort*)((char*)d_ws + WB);
    const int nb = NB_W + (int)((size_t)M_DIM * IN_DIM / 8 / 256);  // 40960
    prep<<<nb, 256, 0, stream>>>(x, q, am, xb, w);
    gemm256<<<(M_DIM / 256) * (OUT_DIM / 256), 512, 0, stream>>>(xb, w, y);
  } else {
    prep<<<NB_W, 256, 0, stream>>>(x, q, am, nullptr, w);
    gemm_fb<<<(M_DIM / 128) * (OUT_DIM / 128), 256, 0, stream>>>(x, w, y);
  }
}